// Round 1
// baseline (401.997 us; speedup 1.0000x reference)
//
#include <hip/hip_runtime.h>
#include <cstdint>
#include <cstddef>

typedef __attribute__((ext_vector_type(8))) short short8;
typedef __attribute__((ext_vector_type(4))) float floatx4;

__device__ __forceinline__ unsigned short f2bf(float f) {
    unsigned int u = __builtin_bit_cast(unsigned int, f);
    u += 0x7fffu + ((u >> 16) & 1u);
    return (unsigned short)(u >> 16);
}
__device__ __forceinline__ float bflo(unsigned int u) {
    return __builtin_bit_cast(float, u << 16);
}
__device__ __forceinline__ short8 pack8(float4 a, float4 b) {
    short8 r;
    r[0] = (short)f2bf(a.x); r[1] = (short)f2bf(a.y);
    r[2] = (short)f2bf(a.z); r[3] = (short)f2bf(a.w);
    r[4] = (short)f2bf(b.x); r[5] = (short)f2bf(b.y);
    r[6] = (short)f2bf(b.z); r[7] = (short)f2bf(b.w);
    return r;
}

// ---------------------------------------------------------------------------
// Batched GEMM. Tile 64(M) x 128(N) x 32(K). Block 256 = 4 waves, each 64x32.
// mode 0: NT, W f32 (N,K), out bf16            (kv projections)
// mode 1: NT, W f32 (N,K), out f32 split-K     (qhead / inproj / outproj)
// mode 2: NN, W f32 (K,N) k-major, out f32     (lifts; split-K via atomics,
//                                               bias==nullptr -> no bias)
// LDS double-buffered, ONE barrier per K-step:
//   barrier -> frag-read buf[cur] -> MFMA -> stage buf[cur^1] from regs
//   -> issue global loads for t+2. Loads get ~2 iterations to cover HBM
//   latency (was ~0.3 iterations -> 600cy stall every step, MfmaUtil 6%).
// mode-2 B tile swizzled: col ^= (row&8)<<1 breaks the 4-way read conflict
// (row stride 132 f32: quad*8*132 % 32 == 0 put all quads on same banks).
// ---------------------------------------------------------------------------
struct SubGemm {
    const float* A; const float* W; const float* bias;
    float* Cf; unsigned short* Ch;
    int K, N, Kc, nj, ni, nkz, mode, ldc;
};
struct GemmBatch { SubGemm d[16]; int start[16]; int nd; };

__global__ __launch_bounds__(256) void gemm_batch(GemmBatch gb)
{
    __shared__ short As[2][64 * 40];
    __shared__ __align__(16) char Braw[2][32 * 132 * 4];

    const int bx = blockIdx.x;
    int di = 0;
#pragma unroll 1
    for (int i = 1; i < gb.nd; ++i) if (bx >= gb.start[i]) di = i;
    const SubGemm g = gb.d[di];
    int local = bx - gb.start[di];
    const int jb = local % g.nj; local /= g.nj;
    const int ib = local % g.ni;
    const int kz = local / g.ni;

    const int tid = threadIdx.x;
    const int w = tid >> 6, lane = tid & 63;
    const int quad = lane >> 4, l16 = lane & 15;
    const int noff = w * 32;

    const int rA = tid >> 2, cA = (tid & 3) * 8;
    const float* pa = g.A + (size_t)(ib * 64 + rA) * g.K + kz * g.Kc + cA;

    floatx4 acc[4][2] = {};

    if (g.mode <= 1) {
        const int rB = tid >> 1, cB = (tid & 1) * 16;
        const float* pb = g.W + (size_t)(jb * 128 + rB) * g.K + kz * g.Kc + cB;
        float4 a0 = *(const float4*)(pa), a1 = *(const float4*)(pa + 4);
        float4 b0 = *(const float4*)(pb),     b1 = *(const float4*)(pb + 4);
        float4 b2 = *(const float4*)(pb + 8), b3 = *(const float4*)(pb + 12);
        {   // stage T0 -> buf0
            short* Asp = As[0]; short* Bsp = (short*)Braw[0];
            *(short8*)&Asp[rA * 40 + cA]     = pack8(a0, a1);
            *(short8*)&Bsp[rB * 40 + cB]     = pack8(b0, b1);
            *(short8*)&Bsp[rB * 40 + cB + 8] = pack8(b2, b3);
        }
        if (g.Kc > 32) {   // load T1
            pa += 32; pb += 32;
            a0 = *(const float4*)(pa);     a1 = *(const float4*)(pa + 4);
            b0 = *(const float4*)(pb);     b1 = *(const float4*)(pb + 4);
            b2 = *(const float4*)(pb + 8); b3 = *(const float4*)(pb + 12);
        }
        int cur = 0;
#pragma unroll 1
        for (int k0 = 0; k0 < g.Kc; k0 += 32) {
            __syncthreads();
            const short* Asc = As[cur];
            const short* Bsc = (const short*)Braw[cur];
            short8 af[4], bfr[2];
#pragma unroll
            for (int r = 0; r < 4; ++r)
                af[r] = *(const short8*)&Asc[(r * 16 + l16) * 40 + quad * 8];
#pragma unroll
            for (int c = 0; c < 2; ++c)
                bfr[c] = *(const short8*)&Bsc[(noff + c * 16 + l16) * 40 + quad * 8];
#pragma unroll
            for (int r = 0; r < 4; ++r)
#pragma unroll
                for (int c = 0; c < 2; ++c)
                    acc[r][c] = __builtin_amdgcn_mfma_f32_16x16x32_bf16(af[r], bfr[c], acc[r][c], 0, 0, 0);
            if (k0 + 32 < g.Kc) {   // stage T(t+1) -> buf^1 (waits vmcnt)
                short* Asn = As[cur ^ 1]; short* Bsn = (short*)Braw[cur ^ 1];
                *(short8*)&Asn[rA * 40 + cA]     = pack8(a0, a1);
                *(short8*)&Bsn[rB * 40 + cB]     = pack8(b0, b1);
                *(short8*)&Bsn[rB * 40 + cB + 8] = pack8(b2, b3);
                if (k0 + 64 < g.Kc) {   // issue loads T(t+2)
                    pa += 32; pb += 32;
                    a0 = *(const float4*)(pa);     a1 = *(const float4*)(pa + 4);
                    b0 = *(const float4*)(pb);     b1 = *(const float4*)(pb + 4);
                    b2 = *(const float4*)(pb + 8); b3 = *(const float4*)(pb + 12);
                }
            }
            cur ^= 1;
        }
    } else {
        const int rK = tid >> 3, cN = (tid & 7) * 16;
        const int cNs = cN ^ ((rK & 8) << 1);       // swizzled store column
        const float* pb = g.W + (size_t)(kz * g.Kc + rK) * g.N + jb * 128 + cN;
        float4 a0 = *(const float4*)(pa), a1 = *(const float4*)(pa + 4);
        float4 b0 = *(const float4*)(pb),     b1 = *(const float4*)(pb + 4);
        float4 b2 = *(const float4*)(pb + 8), b3 = *(const float4*)(pb + 12);
        {   // stage T0 -> buf0
            short* Asp = As[0]; float* Bp = (float*)Braw[0];
            *(short8*)&Asp[rA * 40 + cA] = pack8(a0, a1);
            *(float4*)&Bp[rK * 132 + cNs]      = b0;
            *(float4*)&Bp[rK * 132 + cNs + 4]  = b1;
            *(float4*)&Bp[rK * 132 + cNs + 8]  = b2;
            *(float4*)&Bp[rK * 132 + cNs + 12] = b3;
        }
        if (g.Kc > 32) {   // load T1
            pa += 32; pb += (size_t)32 * g.N;
            a0 = *(const float4*)(pa);     a1 = *(const float4*)(pa + 4);
            b0 = *(const float4*)(pb);     b1 = *(const float4*)(pb + 4);
            b2 = *(const float4*)(pb + 8); b3 = *(const float4*)(pb + 12);
        }
        int cur = 0;
#pragma unroll 1
        for (int k0 = 0; k0 < g.Kc; k0 += 32) {
            __syncthreads();
            const short* Asc = As[cur];
            const float* Bc = (const float*)Braw[cur];
            short8 af[4], bfr[2];
#pragma unroll
            for (int r = 0; r < 4; ++r)
                af[r] = *(const short8*)&Asc[(r * 16 + l16) * 40 + quad * 8];
#pragma unroll
            for (int c = 0; c < 2; ++c) {
                // rows quad*8+i -> row&8 == (quad&1)*8, same swizzle for all i
                const int colb = (noff + c * 16 + l16) ^ ((quad & 1) << 4);
#pragma unroll
                for (int i = 0; i < 8; ++i)
                    bfr[c][i] = (short)f2bf(Bc[(quad * 8 + i) * 132 + colb]);
            }
#pragma unroll
            for (int r = 0; r < 4; ++r)
#pragma unroll
                for (int c = 0; c < 2; ++c)
                    acc[r][c] = __builtin_amdgcn_mfma_f32_16x16x32_bf16(af[r], bfr[c], acc[r][c], 0, 0, 0);
            if (k0 + 32 < g.Kc) {
                short* Asn = As[cur ^ 1]; float* Bn = (float*)Braw[cur ^ 1];
                *(short8*)&Asn[rA * 40 + cA] = pack8(a0, a1);
                *(float4*)&Bn[rK * 132 + cNs]      = b0;
                *(float4*)&Bn[rK * 132 + cNs + 4]  = b1;
                *(float4*)&Bn[rK * 132 + cNs + 8]  = b2;
                *(float4*)&Bn[rK * 132 + cNs + 12] = b3;
                if (k0 + 64 < g.Kc) {
                    pa += 32; pb += (size_t)32 * g.N;
                    a0 = *(const float4*)(pa);     a1 = *(const float4*)(pa + 4);
                    b0 = *(const float4*)(pb);     b1 = *(const float4*)(pb + 4);
                    b2 = *(const float4*)(pb + 8); b3 = *(const float4*)(pb + 12);
                }
            }
            cur ^= 1;
        }
    }

#pragma unroll
    for (int r = 0; r < 4; ++r)
#pragma unroll
        for (int c = 0; c < 2; ++c) {
            const int col = jb * 128 + noff + c * 16 + l16;
            const float bj = (g.bias == nullptr) ? 0.f
                           : ((g.mode == 1 && kz != 0) ? 0.f : g.bias[col]);
#pragma unroll
            for (int q = 0; q < 4; ++q) {
                const int row = ib * 64 + r * 16 + quad * 4 + q;
                const float v = acc[r][c][q] + bj;
                if (g.mode == 0)
                    g.Ch[(size_t)row * g.ldc + col] = f2bf(v);
                else if (g.mode == 1) {
                    if (g.nkz > 1) atomicAdd(&g.Cf[(size_t)row * g.ldc + col], v);
                    else           g.Cf[(size_t)row * g.ldc + col] = v;
                } else {
                    if (g.nkz > 1) atomicAdd(&g.Cf[(size_t)row * g.ldc + col], v);
                    else           g.Cf[(size_t)row * g.ldc + col] = v;
                }
            }
        }
}

// ---------------------------------------------------------------------------
// qk_batch: S(64b x 128m tile) = 0.125 * Q_h @ K_h^T, all 28 heads batched.
// Grid (16 m-tiles, 28 heads). Block 256.
// ---------------------------------------------------------------------------
__global__ __launch_bounds__(256) void qk_batch(
    const float* __restrict__ qp_t, const float* __restrict__ qp_p, const float* __restrict__ qp_c,
    const unsigned short* __restrict__ kv_t, const unsigned short* __restrict__ kv_p, const unsigned short* __restrict__ kv_c,
    float* __restrict__ S_t, float* __restrict__ S_p, float* __restrict__ S_c)
{
    __shared__ short As[64 * 72];
    __shared__ short Bs[128 * 72];
    const int hy = blockIdx.y;
    const float* qp; const unsigned short* kv; float* S; int d, h;
    if (hy < 4)       { qp = qp_t; kv = kv_t; S = S_t; d = 256;  h = hy; }
    else if (hy < 12) { qp = qp_p; kv = kv_p; S = S_p; d = 512;  h = hy - 4; }
    else              { qp = qp_c; kv = kv_c; S = S_c; d = 1024; h = hy - 12; }

    const int j0 = blockIdx.x * 128;
    const int tid = threadIdx.x;
    const int w = tid >> 6, lane = tid & 63;
    const int quad = lane >> 4, l16 = lane & 15;
    const int noff = w * 32;
    const int twoD = 2 * d;

    {
        const int b = tid >> 2, kc = (tid & 3) * 16;
        const float* ga = qp + (size_t)b * d + h * 64 + kc;
        float4 a0 = *(const float4*)(ga + 0), a1 = *(const float4*)(ga + 4);
        float4 a2 = *(const float4*)(ga + 8), a3 = *(const float4*)(ga + 12);
        *(short8*)&As[b * 72 + kc + 0] = pack8(a0, a1);
        *(short8*)&As[b * 72 + kc + 8] = pack8(a2, a3);
    }
    {
        const int m = tid >> 1, hf = (tid & 1) * 32;
        const unsigned short* gb = kv + (size_t)(j0 + m) * twoD + h * 64 + hf;
        uint4 b0 = *(const uint4*)(gb + 0),  b1 = *(const uint4*)(gb + 8);
        uint4 b2 = *(const uint4*)(gb + 16), b3 = *(const uint4*)(gb + 24);
        *(uint4*)&Bs[m * 72 + hf + 0]  = b0;
        *(uint4*)&Bs[m * 72 + hf + 8]  = b1;
        *(uint4*)&Bs[m * 72 + hf + 16] = b2;
        *(uint4*)&Bs[m * 72 + hf + 24] = b3;
    }
    __syncthreads();

    floatx4 acc[4][2] = {};
#pragma unroll
    for (int k0 = 0; k0 < 64; k0 += 32) {
        short8 af[4], bfr[2];
#pragma unroll
        for (int r = 0; r < 4; ++r)
            af[r] = *(const short8*)&As[(r * 16 + l16) * 72 + k0 + quad * 8];
#pragma unroll
        for (int c = 0; c < 2; ++c)
            bfr[c] = *(const short8*)&Bs[(noff + c * 16 + l16) * 72 + k0 + quad * 8];
#pragma unroll
        for (int r = 0; r < 4; ++r)
#pragma unroll
            for (int c = 0; c < 2; ++c)
                acc[r][c] = __builtin_amdgcn_mfma_f32_16x16x32_bf16(af[r], bfr[c], acc[r][c], 0, 0, 0);
    }
#pragma unroll
    for (int r = 0; r < 4; ++r)
#pragma unroll
        for (int c = 0; c < 2; ++c) {
            int col = j0 + noff + c * 16 + l16;
#pragma unroll
            for (int q = 0; q < 4; ++q) {
                int row = r * 16 + quad * 4 + q;
                S[((size_t)h * 64 + row) * 2048 + col] = acc[r][c][q] * 0.125f;
            }
        }
}

// ---------------------------------------------------------------------------
// softmax_pv_batch: per (head, b): softmax over S row, then P @ V_h.
// Grid (28, 64). Block 256.
// ---------------------------------------------------------------------------
__global__ __launch_bounds__(256) void softmax_pv_batch(
    const float* __restrict__ S_t, const float* __restrict__ S_p, const float* __restrict__ S_c,
    const unsigned short* __restrict__ kv_t, const unsigned short* __restrict__ kv_p, const unsigned short* __restrict__ kv_c,
    const uint8_t* __restrict__ mask,
    float* __restrict__ o_t, float* __restrict__ o_p, float* __restrict__ o_c)
{
    const int hy = blockIdx.x, b = blockIdx.y;
    const float* S; const unsigned short* kv; float* o; int d, h;
    if (hy < 4)       { S = S_t; kv = kv_t; o = o_t; d = 256;  h = hy; }
    else if (hy < 12) { S = S_p; kv = kv_p; o = o_p; d = 512;  h = hy - 4; }
    else              { S = S_c; kv = kv_c; o = o_c; d = 1024; h = hy - 12; }

    const int tid = threadIdx.x;
    __shared__ __align__(16) float sc[2048];
    __shared__ float red[4];
    __shared__ float part[4][64];
    __shared__ float s_max, s_sum;

    const float* Sr = S + ((size_t)h * 64 + b) * 2048;
    const uint8_t* mr = mask + (size_t)b * 2048;

    float lmax = -1e30f;
    for (int m = tid; m < 2048; m += 256) {
        float s = Sr[m];
        if (mr[m]) s = -1e9f;
        sc[m] = s;
        lmax = fmaxf(lmax, s);
    }
#pragma unroll
    for (int off = 32; off; off >>= 1) lmax = fmaxf(lmax, __shfl_down(lmax, off));
    if ((tid & 63) == 0) red[tid >> 6] = lmax;
    __syncthreads();
    if (tid == 0) s_max = fmaxf(fmaxf(red[0], red[1]), fmaxf(red[2], red[3]));
    __syncthreads();
    const float mx = s_max;

    float lsum = 0.f;
    for (int m = tid; m < 2048; m += 256) {
        float e = __expf(sc[m] - mx);
        sc[m] = e;
        lsum += e;
    }
#pragma unroll
    for (int off = 32; off; off >>= 1) lsum += __shfl_down(lsum, off);
    if ((tid & 63) == 0) red[tid >> 6] = lsum;
    __syncthreads();
    if (tid == 0) s_sum = red[0] + red[1] + red[2] + red[3];
    __syncthreads();

    const int lane = tid & 63, w = tid >> 6;
    const int twoD = 2 * d;
    const unsigned short* vcol = kv + d + h * 64 + lane;
    float acc = 0.f;
    const int m0 = w * 512;
#pragma unroll 1
    for (int m = m0; m < m0 + 512; m += 8) {
#pragma unroll
        for (int j = 0; j < 8; ++j)
            acc += sc[m + j] * bflo((unsigned int)vcol[(size_t)(m + j) * twoD]);
    }
    part[w][lane] = acc;
    __syncthreads();
    if (tid < 64) {
        float r = (part[0][tid] + part[1][tid] + part[2][tid] + part[3][tid]) / s_sum;
        o[(size_t)b * d + h * 64 + tid] = r;
    }
}

// ---------------------------------------------------------------------------
// layernorm in place; also adds the lift bias (lifts now atomically
// accumulate without bias): row = b*16 + l, slot l -> blift row.
// ---------------------------------------------------------------------------
__global__ __launch_bounds__(256) void ln_kernel(
    float* __restrict__ x, const float* __restrict__ g, const float* __restrict__ bb,
    const float* __restrict__ blt, const float* __restrict__ blp, const float* __restrict__ blc)
{
    const int row = blockIdx.x;
    const int l = row & 15;
    const float* lb = (l < 4)  ? (blt + (size_t)l * 4096)
                    : (l < 12) ? (blp + (size_t)(l - 4) * 4096)
                               : (blc + (size_t)(l - 12) * 4096);
    float* xr = x + (size_t)row * 4096;
    const int tid = threadIdx.x;
    float v[16];
    float sum = 0.f, sumsq = 0.f;
#pragma unroll
    for (int i = 0; i < 16; ++i) {
        int e = tid + i * 256;
        v[i] = xr[e] + lb[e];
        sum += v[i];
        sumsq += v[i] * v[i];
    }
    __shared__ float rs[4], rq[4];
#pragma unroll
    for (int off = 32; off; off >>= 1) {
        sum += __shfl_down(sum, off);
        sumsq += __shfl_down(sumsq, off);
    }
    if ((tid & 63) == 0) { rs[tid >> 6] = sum; rq[tid >> 6] = sumsq; }
    __syncthreads();
    const float ts = rs[0] + rs[1] + rs[2] + rs[3];
    const float tq = rq[0] + rq[1] + rq[2] + rq[3];
    const float mu = ts * (1.f / 4096.f);
    const float var = tq * (1.f / 4096.f) - mu * mu;
    const float r = rsqrtf(var + 1e-5f);
#pragma unroll
    for (int i = 0; i < 16; ++i) {
        int e = tid + i * 256;
        xr[e] = (v[i] - mu) * r * g[e] + bb[e];
    }
}

// ---------------------------------------------------------------------------
static void addg(GemmBatch& G, int& tot,
                 const float* A, const float* W, const float* bias,
                 float* Cf, unsigned short* Ch,
                 int K, int N, int Kc, int nj, int ni, int nkz, int mode, int ldc)
{
    SubGemm& s = G.d[G.nd];
    s.A = A; s.W = W; s.bias = bias; s.Cf = Cf; s.Ch = Ch;
    s.K = K; s.N = N; s.Kc = Kc; s.nj = nj; s.ni = ni; s.nkz = nkz;
    s.mode = mode; s.ldc = ldc;
    G.start[G.nd] = tot;
    tot += nj * ni * nkz;
    G.nd++;
}

extern "C" void kernel_launch(void* const* d_in, const int* in_sizes, int n_in,
                              void* d_out, int out_size, void* d_ws, size_t ws_size,
                              hipStream_t stream)
{
    const float*   hs     = (const float*)d_in[0];
    const float*   fib_t  = (const float*)d_in[1];
    const float*   fib_p  = (const float*)d_in[2];
    const float*   fib_c  = (const float*)d_in[3];
    const uint8_t* mask   = (const uint8_t*)d_in[4];
    const float* Wq_t   = (const float*)d_in[5];  const float* bq_t   = (const float*)d_in[6];
    const float* Wq_p   = (const float*)d_in[7];  const float* bq_p   = (const float*)d_in[8];
    const float* Wq_c   = (const float*)d_in[9];  const float* bq_c   = (const float*)d_in[10];
    const float* Wqkv_t = (const float*)d_in[11]; const float* bqkv_t = (const float*)d_in[12];
    const float* Wo_t   = (const float*)d_in[13]; const float* bo_t   = (const float*)d_in[14];
    const float* Wqkv_p = (const float*)d_in[15]; const float* bqkv_p = (const float*)d_in[16];
    const float* Wo_p   = (const float*)d_in[17]; const float* bo_p   = (const float*)d_in[18];
    const float* Wqkv_c = (const float*)d_in[19]; const float* bqkv_c = (const float*)d_in[20];
    const float* Wo_c   = (const float*)d_in[21]; const float* bo_c   = (const float*)d_in[22];
    const float* Wl_t   = (const float*)d_in[23]; const float* bl_t   = (const float*)d_in[24];
    const float* Wl_p   = (const float*)d_in[25]; const float* bl_p   = (const float*)d_in[26];
    const float* Wl_c   = (const float*)d_in[27]; const float* bl_c   = (const float*)d_in[28];
    const float* ln_g   = (const float*)d_in[29]; const float* ln_b   = (const float*)d_in[30];

    char* wsb = (char*)d_ws;
    float* q_t  = (float*)wsb; wsb += 64 * 256 * 4;
    float* q_p  = (float*)wsb; wsb += 64 * 512 * 4;
    float* q_c  = (float*)wsb; wsb += 64 * 1024 * 4;
    float* qp_t = (float*)wsb; wsb += 64 * 256 * 4;
    float* qp_p = (float*)wsb; wsb += 64 * 512 * 4;
    float* qp_c = (float*)wsb; wsb += 64 * 1024 * 4;
    float* po_t = (float*)wsb; wsb += 64 * 256 * 4;
    float* po_p = (float*)wsb; wsb += 64 * 512 * 4;
    float* po_c = (float*)wsb; wsb += 64 * 1024 * 4;
    size_t zbytes = (size_t)(wsb - (char*)d_ws);
    float* o_t  = (float*)wsb; wsb += 64 * 256 * 4;
    float* o_p  = (float*)wsb; wsb += 64 * 512 * 4;
    float* o_c  = (float*)wsb; wsb += 64 * 1024 * 4;
    unsigned short* kv_t = (unsigned short*)wsb; wsb += 2048 * 512 * 2;
    unsigned short* kv_p = (unsigned short*)wsb; wsb += 2048 * 1024 * 2;
    unsigned short* kv_c = (unsigned short*)wsb; wsb += 2048 * 2048 * 2;
    float* S_t = (float*)wsb; wsb += (size_t)4  * 64 * 2048 * 4;
    float* S_p = (float*)wsb; wsb += (size_t)8  * 64 * 2048 * 4;
    float* S_c = (float*)wsb; wsb += (size_t)16 * 64 * 2048 * 4;
    float* out = (float*)d_out;

    const dim3 blk(256);
    hipMemsetAsync(d_ws, 0, zbytes, stream);
    hipMemsetAsync(d_out, 0, (size_t)out_size, stream);   // lifts accumulate atomically

    // ---- launch 1: kv projections (bf16 out) + bundle query heads (split-K)
    {
        GemmBatch G{}; int tot = 0; G.nd = 0;
        addg(G, tot, fib_c, Wqkv_c + 1024 * 1024, bqkv_c + 1024, nullptr, kv_c, 1024, 2048, 1024, 16, 32, 1, 0, 2048);
        addg(G, tot, fib_p, Wqkv_p + 512 * 512,   bqkv_p + 512,  nullptr, kv_p, 512,  1024, 512,  8,  32, 1, 0, 1024);
        addg(G, tot, fib_t, Wqkv_t + 256 * 256,   bqkv_t + 256,  nullptr, kv_t, 256,  512,  256,  4,  32, 1, 0, 512);
        addg(G, tot, hs, Wq_c, bq_c, q_c, nullptr, 4096, 1024, 256, 8, 1, 16, 1, 1024);
        addg(G, tot, hs, Wq_p, bq_p, q_p, nullptr, 4096, 512,  256, 4, 1, 16, 1, 512);
        addg(G, tot, hs, Wq_t, bq_t, q_t, nullptr, 4096, 256,  256, 2, 1, 16, 1, 256);
        gemm_batch<<<dim3(tot), blk, 0, stream>>>(G);
    }

    // ---- launch 2: q in-proj
    {
        GemmBatch G{}; int tot = 0; G.nd = 0;
        addg(G, tot, q_c, Wqkv_c, bqkv_c, qp_c, nullptr, 1024, 1024, 128, 8, 1, 8, 1, 1024);
        addg(G, tot, q_p, Wqkv_p, bqkv_p, qp_p, nullptr, 512,  512,  64,  4, 1, 8, 1, 512);
        addg(G, tot, q_t, Wqkv_t, bqkv_t, qp_t, nullptr, 256,  256,  64,  2, 1, 4, 1, 256);
        gemm_batch<<<dim3(tot), blk, 0, stream>>>(G);
    }

    // ---- launch 3/4: attention
    qk_batch<<<dim3(16, 28), blk, 0, stream>>>(qp_t, qp_p, qp_c, kv_t, kv_p, kv_c, S_t, S_p, S_c);
    softmax_pv_batch<<<dim3(28, 64), blk, 0, stream>>>(S_t, S_p, S_c, kv_t, kv_p, kv_c, mask, o_t, o_p, o_c);

    // ---- launch 5: out-proj
    {
        GemmBatch G{}; int tot = 0; G.nd = 0;
        addg(G, tot, o_c, Wo_c, bo_c, po_c, nullptr, 1024, 1024, 128, 8, 1, 8, 1, 1024);
        addg(G, tot, o_p, Wo_p, bo_p, po_p, nullptr, 512,  512,  64,  4, 1, 8, 1, 512);
        addg(G, tot, o_t, Wo_t, bo_t, po_t, nullptr, 256,  256,  64,  2, 1, 4, 1, 256);
        gemm_batch<<<dim3(tot), blk, 0, stream>>>(G);
    }

    // ---- launch 6: lifts (NN mode, split-K, atomic accumulate; bias in LN)
    {
        GemmBatch G{}; int tot = 0; G.nd = 0;
        for (int z = 0; z < 4; ++z)
            addg(G, tot, po_c, Wl_c + (size_t)z * 1024 * 4096, nullptr,
                 out + (size_t)(12 + z) * 4096, nullptr, 1024, 4096, 256, 32, 1, 4, 2, 16 * 4096);
        for (int z = 0; z < 8; ++z)
            addg(G, tot, po_p, Wl_p + (size_t)z * 512 * 4096, nullptr,
                 out + (size_t)(4 + z) * 4096, nullptr, 512, 4096, 256, 32, 1, 2, 2, 16 * 4096);
        for (int z = 0; z < 4; ++z)
            addg(G, tot, po_t, Wl_t + (size_t)z * 256 * 4096, nullptr,
                 out + (size_t)z * 4096, nullptr, 256, 4096, 256, 32, 1, 1, 2, 16 * 4096);
        gemm_batch<<<dim3(tot), blk, 0, stream>>>(G);
    }

    // ---- launch 7: layernorm in place (+ lift bias)
    ln_kernel<<<dim3(1024), blk, 0, stream>>>(out, ln_g, ln_b, bl_t, bl_p, bl_c);
}